// Round 18
// baseline (46.253 us; speedup 1.0000x reference)
//
#include <hip/hip_runtime.h>

#define H 1024
#define W 1024
#define TY 8
#define NT 64               /* one wave per block */
#define RS 10               /* ring slots */
#define PCOL 264            /* ring plane cols: 4 halo + 256 own + 4 halo */
#define NBK 64              /* reduction buckets */

__global__ void ncc_zero(double* acc) {
    if (threadIdx.x < NBK) acc[threadIdx.x] = 0.0;
}

__global__ void ncc_finalize(const double* __restrict__ acc, float* __restrict__ out) {
    double s = 0.0;
    #pragma unroll
    for (int i = 0; i < NBK; ++i) s += acc[i];
    out[0] = 1.0f - (float)(s * (1.0 / 8388608.0));
}

// pack 2 f32 -> u32 of 2 bf16 (lo [15:0], hi [31:16]), RNE
__device__ __forceinline__ unsigned pk2(float lo, float hi) {
    unsigned r;
    asm("v_cvt_pk_bf16_f32 %0, %1, %2" : "=v"(r) : "v"(lo), "v"(hi));
    return r;
}
__device__ __forceinline__ float ulo(unsigned u) { return __uint_as_float(u << 16); }
__device__ __forceinline__ float uhi(unsigned u) { return __uint_as_float(u & 0xffff0000u); }

__global__ __launch_bounds__(NT) void ncc_main(
    const float* __restrict__ Jg,  // y_pred
    const float* __restrict__ Ig,  // y_true
    double* __restrict__ acc)
{
    __shared__ unsigned short ring[RS][2][PCOL];   // bf16 rows, [slot][I/J][col]: 10.3 KB

    const int n     = blockIdx.x;
    const int b     = n & 7;            // image (== XCD round-robin)
    const int rest  = n >> 3;
    const int panel = rest & 3;         // 256-col panel
    const int strip = rest >> 2;        // 8-row strip
    const int y0    = strip * TY;
    const int lane  = threadIdx.x;
    const int wb    = panel << 8;
    const int x0    = wb + (lane << 2); // own 4 global cols
    const int p0    = lane << 2;        // ring read col base (12 cols p0..p0+11)
    const int pown  = p0 + 4;           // ring own col base

    const float* __restrict__ Ib = Ig + (size_t)b * (H * W);
    const float* __restrict__ Jb = Jg + (size_t)b * (H * W);

    // halo duty: lane0 I-left4, lane1 J-left4, lane2 I-right4, lane3 J-right4
    const bool  hl  = (lane < 4);
    const int   hx  = (lane < 2) ? (wb - 4) : (wb + 256);
    const float mhx = (hl && (unsigned)hx <= (unsigned)(W - 4)) ? 1.0f : 0.0f;
    const int   hxc = min(max(hx, 0), W - 4);
    const float* hbase = (lane & 1) ? Jb : Ib;
    const int   hp  = (lane < 2) ? 0 : 260;   // ring col of halo write
    const int   him = lane & 1;               // image plane for halo write

    float rI[4]={0,0,0,0}, rJ[4]={0,0,0,0}, rII[4]={0,0,0,0}, rJJ[4]={0,0,0,0}, rIJ[4]={0,0,0,0};
    float accv = 0.0f;
    const float inv = 1.0f / 81.0f;

    float4 Pi, Pj, Ph = {0, 0, 0, 0};
    float  Pm;

#define FLOAD(yy) do {                                                              \
        const int r_ = (yy);                                                        \
        Pm = ((unsigned)r_ < (unsigned)H) ? 1.0f : 0.0f;                            \
        const int rc_ = min(max(r_, 0), H - 1);                                     \
        Pi = *(const float4*)(Ib + (size_t)rc_ * W + x0);                           \
        Pj = *(const float4*)(Jb + (size_t)rc_ * W + x0);                           \
        if (hl) Ph = *(const float4*)(hbase + (size_t)rc_ * W + hxc);               \
    } while (0)

#define PACKW(sl) do {                                                              \
        const unsigned i01_ = pk2(Pi.x * Pm, Pi.y * Pm);                            \
        const unsigned i23_ = pk2(Pi.z * Pm, Pi.w * Pm);                            \
        const unsigned j01_ = pk2(Pj.x * Pm, Pj.y * Pm);                            \
        const unsigned j23_ = pk2(Pj.z * Pm, Pj.w * Pm);                            \
        *(uint2*)&ring[sl][0][pown] = make_uint2(i01_, i23_);                       \
        *(uint2*)&ring[sl][1][pown] = make_uint2(j01_, j23_);                       \
        if (hl) {                                                                   \
            const float mm_ = Pm * mhx;                                             \
            const unsigned h01_ = pk2(Ph.x * mm_, Ph.y * mm_);                      \
            const unsigned h23_ = pk2(Ph.z * mm_, Ph.w * mm_);                      \
            *(uint2*)&ring[sl][him][hp] = make_uint2(h01_, h23_);                   \
        }                                                                           \
    } while (0)

#define READS(sl, A, B, C, D, E, F) do {                                            \
        A = *(const uint2*)&ring[sl][0][p0];                                        \
        B = *(const uint2*)&ring[sl][0][p0 + 4];                                    \
        C = *(const uint2*)&ring[sl][0][p0 + 8];                                    \
        D = *(const uint2*)&ring[sl][1][p0];                                        \
        E = *(const uint2*)&ring[sl][1][p0 + 4];                                    \
        F = *(const uint2*)&ring[sl][1][p0 + 8];                                    \
    } while (0)

// unpack 12 cols x 2 images, fold 5 quantities' horizontal 9-sums with sign SG.
// Term-identical arithmetic for +/- of the same packed row -> clean cancellation.
#define FOLD12(Ua, Ub, Uc, Va, Vb, Vc, SG) do {                                     \
        const float i0=ulo(Ua.x), i1=uhi(Ua.x), i2=ulo(Ua.y), i3=uhi(Ua.y);         \
        const float i4=ulo(Ub.x), i5=uhi(Ub.x), i6=ulo(Ub.y), i7=uhi(Ub.y);         \
        const float i8=ulo(Uc.x), i9=uhi(Uc.x), i10=ulo(Uc.y), i11=uhi(Uc.y);       \
        const float j0=ulo(Va.x), j1=uhi(Va.x), j2=ulo(Va.y), j3=uhi(Va.y);         \
        const float j4=ulo(Vb.x), j5=uhi(Vb.x), j6=ulo(Vb.y), j7=uhi(Vb.y);         \
        const float j8=ulo(Vc.x), j9=uhi(Vc.x), j10=ulo(Vc.y), j11=uhi(Vc.y);       \
        { float s_ = i0+i1+i2+i3+i4+i5+i6+i7+i8;                                    \
          rI[0] += SG*s_; s_ += i9-i0;  rI[1] += SG*s_;                             \
          s_ += i10-i1;   rI[2] += SG*s_; s_ += i11-i2; rI[3] += SG*s_; }           \
        { float s_ = j0+j1+j2+j3+j4+j5+j6+j7+j8;                                    \
          rJ[0] += SG*s_; s_ += j9-j0;  rJ[1] += SG*s_;                             \
          s_ += j10-j1;   rJ[2] += SG*s_; s_ += j11-j2; rJ[3] += SG*s_; }           \
        { const float q0=i0*i0,q1=i1*i1,q2=i2*i2,q3=i3*i3,q4=i4*i4,q5=i5*i5;        \
          const float q6=i6*i6,q7=i7*i7,q8=i8*i8,q9=i9*i9,q10=i10*i10,q11=i11*i11;  \
          float s_ = q0+q1+q2+q3+q4+q5+q6+q7+q8;                                    \
          rII[0] += SG*s_; s_ += q9-q0;  rII[1] += SG*s_;                           \
          s_ += q10-q1;    rII[2] += SG*s_; s_ += q11-q2; rII[3] += SG*s_; }        \
        { const float q0=j0*j0,q1=j1*j1,q2=j2*j2,q3=j3*j3,q4=j4*j4,q5=j5*j5;        \
          const float q6=j6*j6,q7=j7*j7,q8=j8*j8,q9=j9*j9,q10=j10*j10,q11=j11*j11;  \
          float s_ = q0+q1+q2+q3+q4+q5+q6+q7+q8;                                    \
          rJJ[0] += SG*s_; s_ += q9-q0;  rJJ[1] += SG*s_;                           \
          s_ += q10-q1;    rJJ[2] += SG*s_; s_ += q11-q2; rJJ[3] += SG*s_; }        \
        { const float q0=i0*j0,q1=i1*j1,q2=i2*j2,q3=i3*j3,q4=i4*j4,q5=i5*j5;        \
          const float q6=i6*j6,q7=i7*j7,q8=i8*j8,q9=i9*j9,q10=i10*j10,q11=i11*j11;  \
          float s_ = q0+q1+q2+q3+q4+q5+q6+q7+q8;                                    \
          rIJ[0] += SG*s_; s_ += q9-q0;  rIJ[1] += SG*s_;                           \
          s_ += q10-q1;    rIJ[2] += SG*s_; s_ += q11-q2; rIJ[3] += SG*s_; }        \
    } while (0)

#define CC() do {                                                                   \
        _Pragma("unroll")                                                           \
        for (int c = 0; c < 4; ++c) {                                               \
            const float uI    = rI[c] * inv;                                        \
            const float uJ    = rJ[c] * inv;                                        \
            const float cross = rIJ[c] * inv - uI * uJ;                             \
            const float Iv    = rII[c] * inv - uI * uI;                             \
            const float Jv    = rJJ[c] * inv - uJ * uJ;                             \
            accv += cross * rsqrtf(fmaxf(Iv * Jv, 1e-7f));                          \
        }                                                                           \
    } while (0)

    // ---- init: rows y0-4 .. y0+4 -> ring slots 0..8, folded (+) ----
    FLOAD(y0 - 4);
    #pragma unroll 1
    for (int r = 0; r < 9; ++r) {
        PACKW(r);
        asm volatile("" ::: "memory");
        uint2 Ua, Ub, Uc, Va, Vb, Vc;
        READS(r, Ua, Ub, Uc, Va, Vb, Vc);
        asm volatile("" ::: "memory");
        FLOAD(y0 - 3 + r);   // r==8 loads y0+5: the first enter row, ready for k=0
        FOLD12(Ua, Ub, Uc, Va, Vb, Vc, 1.0f);
    }

    // ---- main: 7 slides; cc row y0+k from pre-slide sums ----
    int ls = 0, es = 9;
    #pragma unroll 1
    for (int k = 0; k < TY - 1; ++k) {
        PACKW(es);                         // enter row (prefetched) -> ring
        asm volatile("" ::: "memory");
        uint2 eUa, eUb, eUc, eVa, eVb, eVc;
        uint2 lUa, lUb, lUc, lVa, lVb, lVc;
        READS(es, eUa, eUb, eUc, eVa, eVb, eVc);
        READS(ls, lUa, lUb, lUc, lVa, lVb, lVc);
        asm volatile("" ::: "memory");
        FLOAD(y0 + 6 + k);                 // prefetch next enter row (global, read-once)
        CC();                              // row y0+k — covers DS latency
        FOLD12(eUa, eUb, eUc, eVa, eVb, eVc,  1.0f);
        FOLD12(lUa, lUb, lUc, lVa, lVb, lVc, -1.0f);
        ls += 1;
        es = (es == RS - 1) ? 0 : es + 1;
    }
    CC();                                  // final row y0+7

#undef CC
#undef FOLD12
#undef READS
#undef PACKW
#undef FLOAD

    // wave reduce -> bucketed atomics (64 buckets kill same-address contention)
    #pragma unroll
    for (int off = 32; off > 0; off >>= 1)
        accv += __shfl_down(accv, off);
    if (lane == 0)
        atomicAdd(&acc[n & (NBK - 1)], (double)accv);
}

extern "C" void kernel_launch(void* const* d_in, const int* in_sizes, int n_in,
                              void* d_out, int out_size, void* d_ws, size_t ws_size,
                              hipStream_t stream) {
    const float* y_pred = (const float*)d_in[0];  // Ji
    const float* y_true = (const float*)d_in[1];  // Ii
    float* out = (float*)d_out;
    double* accp = (double*)d_ws;

    ncc_zero<<<dim3(1), dim3(NBK), 0, stream>>>(accp);
    // 8 img x 4 panels x 128 strips = 4096 one-wave blocks; 10.3 KB LDS -> ~15 blocks/CU;
    // every input row fetched from global exactly once (bf16 ring serves re-reads)
    ncc_main<<<dim3(8 * 4 * (H / TY)), dim3(NT), 0, stream>>>(y_pred, y_true, accp);
    ncc_finalize<<<dim3(1), dim3(1), 0, stream>>>(accp, out);
}

// Round 19
// 43.643 us; speedup vs baseline: 1.0598x; 1.0598x over previous
//
#include <hip/hip_runtime.h>

#define H 1024
#define W 1024
#define TY 16
#define NT 64               /* one wave per block */
#define RS 10               /* ring slots (distance 9 + 1) */
#define NG 66               /* uint4 col-groups per slot: 1 halo + 64 own + 1 halo */
#define NBK 64              /* reduction buckets */

__global__ void ncc_zero(double* acc) {
    if (threadIdx.x < NBK) acc[threadIdx.x] = 0.0;
}

__global__ void ncc_finalize(const double* __restrict__ acc, float* __restrict__ out) {
    double s = 0.0;
    #pragma unroll
    for (int i = 0; i < NBK; ++i) s += acc[i];
    out[0] = 1.0f - (float)(s * (1.0 / 8388608.0));
}

// pack 2 f32 -> u32 of 2 bf16 (lo [15:0], hi [31:16]), RNE
__device__ __forceinline__ unsigned pk2(float lo, float hi) {
    unsigned r;
    asm("v_cvt_pk_bf16_f32 %0, %1, %2" : "=v"(r) : "v"(lo), "v"(hi));
    return r;
}
__device__ __forceinline__ float ulo(unsigned u) { return __uint_as_float(u << 16); }
__device__ __forceinline__ float uhi(unsigned u) { return __uint_as_float(u & 0xffff0000u); }

__global__ __launch_bounds__(NT) void ncc_main(
    const float* __restrict__ Jg,  // y_pred
    const float* __restrict__ Ig,  // y_true
    double* __restrict__ acc)
{
    // ring[slot][group]: group g = 4 bf16 cols x 2 images {i01,i23,j01,j23}; 10.3 KB
    __shared__ uint4 ring[RS][NG];

    const int n     = blockIdx.x;
    const int b     = n & 7;            // image (== XCD round-robin)
    const int rest  = n >> 3;
    const int panel = rest & 3;         // 256-col panel
    const int strip = rest >> 2;        // 16-row strip
    const int y0    = strip * TY;
    const int lane  = threadIdx.x;
    const int wb    = panel << 8;
    const int x0    = wb + (lane << 2); // own 4 global cols -> ring group lane+1

    const float* __restrict__ Ib = Ig + (size_t)b * (H * W);
    const float* __restrict__ Jb = Jg + (size_t)b * (H * W);

    // halo duty: lane 0 -> left group 0 (cols wb-4..wb-1), lane 1 -> right group 65
    const bool  hl  = (lane < 2);
    const int   hx  = (lane == 0) ? (wb - 4) : (wb + 256);
    const float mhx = (hl && (unsigned)hx <= (unsigned)(W - 4)) ? 1.0f : 0.0f;
    const int   hxc = min(max(hx, 0), W - 4);
    const int   hg  = (lane == 0) ? 0 : (NG - 1);

    float rI[4]={0,0,0,0}, rJ[4]={0,0,0,0}, rII[4]={0,0,0,0}, rJJ[4]={0,0,0,0}, rIJ[4]={0,0,0,0};
    float accv = 0.0f;
    const float inv = 1.0f / 81.0f;

    float4 Pi, Pj, Phi = {0,0,0,0}, Phj = {0,0,0,0};
    float  Pm;

#define FLOAD(yy) do {                                                              \
        const int r_ = (yy);                                                        \
        Pm = ((unsigned)r_ < (unsigned)H) ? 1.0f : 0.0f;                            \
        const int rc_ = min(max(r_, 0), H - 1);                                     \
        Pi = *(const float4*)(Ib + (size_t)rc_ * W + x0);                           \
        Pj = *(const float4*)(Jb + (size_t)rc_ * W + x0);                           \
        if (hl) {                                                                   \
            Phi = *(const float4*)(Ib + (size_t)rc_ * W + hxc);                     \
            Phj = *(const float4*)(Jb + (size_t)rc_ * W + hxc);                     \
        }                                                                           \
    } while (0)

#define PACKW(sl) do {                                                              \
        uint4 v_;                                                                   \
        v_.x = pk2(Pi.x * Pm, Pi.y * Pm);                                           \
        v_.y = pk2(Pi.z * Pm, Pi.w * Pm);                                           \
        v_.z = pk2(Pj.x * Pm, Pj.y * Pm);                                           \
        v_.w = pk2(Pj.z * Pm, Pj.w * Pm);                                           \
        ring[sl][lane + 1] = v_;                                                    \
        if (hl) {                                                                   \
            const float mm_ = Pm * mhx;                                             \
            uint4 h_;                                                               \
            h_.x = pk2(Phi.x * mm_, Phi.y * mm_);                                   \
            h_.y = pk2(Phi.z * mm_, Phi.w * mm_);                                   \
            h_.z = pk2(Phj.x * mm_, Phj.y * mm_);                                   \
            h_.w = pk2(Phj.z * mm_, Phj.w * mm_);                                   \
            ring[sl][hg] = h_;                                                      \
        }                                                                           \
    } while (0)

#define READS(sl, G0, G1, G2) do {                                                  \
        G0 = ring[sl][lane];                                                        \
        G1 = ring[sl][lane + 1];                                                    \
        G2 = ring[sl][lane + 2];                                                    \
    } while (0)

// unpack 12 cols x 2 images from 3 groups, fold horizontal 9-sums with sign SG
#define FOLD12(G0, G1, G2, SG) do {                                                 \
        const float i0=ulo(G0.x), i1=uhi(G0.x), i2=ulo(G0.y), i3=uhi(G0.y);         \
        const float i4=ulo(G1.x), i5=uhi(G1.x), i6=ulo(G1.y), i7=uhi(G1.y);         \
        const float i8=ulo(G2.x), i9=uhi(G2.x), i10=ulo(G2.y), i11=uhi(G2.y);       \
        const float j0=ulo(G0.z), j1=uhi(G0.z), j2=ulo(G0.w), j3=uhi(G0.w);         \
        const float j4=ulo(G1.z), j5=uhi(G1.z), j6=ulo(G1.w), j7=uhi(G1.w);         \
        const float j8=ulo(G2.z), j9=uhi(G2.z), j10=ulo(G2.w), j11=uhi(G2.w);       \
        { float s_ = i0+i1+i2+i3+i4+i5+i6+i7+i8;                                    \
          rI[0] += SG*s_; s_ += i9-i0;  rI[1] += SG*s_;                             \
          s_ += i10-i1;   rI[2] += SG*s_; s_ += i11-i2; rI[3] += SG*s_; }           \
        { float s_ = j0+j1+j2+j3+j4+j5+j6+j7+j8;                                    \
          rJ[0] += SG*s_; s_ += j9-j0;  rJ[1] += SG*s_;                             \
          s_ += j10-j1;   rJ[2] += SG*s_; s_ += j11-j2; rJ[3] += SG*s_; }           \
        { const float q0=i0*i0,q1=i1*i1,q2=i2*i2,q3=i3*i3,q4=i4*i4,q5=i5*i5;        \
          const float q6=i6*i6,q7=i7*i7,q8=i8*i8,q9=i9*i9,q10=i10*i10,q11=i11*i11;  \
          float s_ = q0+q1+q2+q3+q4+q5+q6+q7+q8;                                    \
          rII[0] += SG*s_; s_ += q9-q0;  rII[1] += SG*s_;                           \
          s_ += q10-q1;    rII[2] += SG*s_; s_ += q11-q2; rII[3] += SG*s_; }        \
        { const float q0=j0*j0,q1=j1*j1,q2=j2*j2,q3=j3*j3,q4=j4*j4,q5=j5*j5;        \
          const float q6=j6*j6,q7=j7*j7,q8=j8*j8,q9=j9*j9,q10=j10*j10,q11=j11*j11;  \
          float s_ = q0+q1+q2+q3+q4+q5+q6+q7+q8;                                    \
          rJJ[0] += SG*s_; s_ += q9-q0;  rJJ[1] += SG*s_;                           \
          s_ += q10-q1;    rJJ[2] += SG*s_; s_ += q11-q2; rJJ[3] += SG*s_; }        \
        { const float q0=i0*j0,q1=i1*j1,q2=i2*j2,q3=i3*j3,q4=i4*j4,q5=i5*j5;        \
          const float q6=i6*j6,q7=i7*j7,q8=i8*j8,q9=i9*j9,q10=i10*j10,q11=i11*j11;  \
          float s_ = q0+q1+q2+q3+q4+q5+q6+q7+q8;                                    \
          rIJ[0] += SG*s_; s_ += q9-q0;  rIJ[1] += SG*s_;                           \
          s_ += q10-q1;    rIJ[2] += SG*s_; s_ += q11-q2; rIJ[3] += SG*s_; }        \
    } while (0)

#define CC() do {                                                                   \
        _Pragma("unroll")                                                           \
        for (int c = 0; c < 4; ++c) {                                               \
            const float uI    = rI[c] * inv;                                        \
            const float uJ    = rJ[c] * inv;                                        \
            const float cross = rIJ[c] * inv - uI * uJ;                             \
            const float Iv    = rII[c] * inv - uI * uI;                             \
            const float Jv    = rJJ[c] * inv - uJ * uJ;                             \
            accv += cross * rsqrtf(fmaxf(Iv * Jv, 1e-7f));                          \
        }                                                                           \
    } while (0)

    // ---- init: rows y0-4 .. y0+4 -> ring slots 0..8, folded (+) ----
    FLOAD(y0 - 4);
    #pragma unroll 1
    for (int r = 0; r < 9; ++r) {
        PACKW(r);
        asm volatile("" ::: "memory");
        uint4 G0, G1, G2;
        READS(r, G0, G1, G2);
        asm volatile("" ::: "memory");
        FLOAD(y0 - 3 + r);   // r==8 loads y0+5: first enter row
        FOLD12(G0, G1, G2, 1.0f);
    }

    // ---- main: TY-1 slides; cc row y0+k from pre-slide sums ----
    int ls = 0, es = 9;
    #pragma unroll 1
    for (int k = 0; k < TY - 1; ++k) {
        PACKW(es);                          // enter row (prefetched) -> ring
        asm volatile("" ::: "memory");
        uint4 e0, e1, e2, l0, l1, l2;
        READS(es, e0, e1, e2);
        READS(ls, l0, l1, l2);
        asm volatile("" ::: "memory");
        FLOAD(y0 + 6 + k);                  // prefetch next enter row (read-once)
        CC();                               // row y0+k — covers DS/VMEM latency
        FOLD12(e0, e1, e2,  1.0f);
        FOLD12(l0, l1, l2, -1.0f);
        ls = (ls == RS - 1) ? 0 : ls + 1;
        es = (es == RS - 1) ? 0 : es + 1;
    }
    CC();                                   // final row y0+TY-1

#undef CC
#undef FOLD12
#undef READS
#undef PACKW
#undef FLOAD

    // wave reduce -> bucketed atomics
    #pragma unroll
    for (int off = 32; off > 0; off >>= 1)
        accv += __shfl_down(accv, off);
    if (lane == 0)
        atomicAdd(&acc[n & (NBK - 1)], (double)accv);
}

extern "C" void kernel_launch(void* const* d_in, const int* in_sizes, int n_in,
                              void* d_out, int out_size, void* d_ws, size_t ws_size,
                              hipStream_t stream) {
    const float* y_pred = (const float*)d_in[0];  // Ji
    const float* y_true = (const float*)d_in[1];  // Ii
    float* out = (float*)d_out;
    double* accp = (double*)d_ws;

    ncc_zero<<<dim3(1), dim3(NBK), 0, stream>>>(accp);
    // 8 img x 4 panels x 64 strips = 2048 one-wave blocks; uint4 ring (10.3 KB);
    // ~8 DS ops/iter (was 22), TY=16 amortizes the 9-row init
    ncc_main<<<dim3(8 * 4 * (H / TY)), dim3(NT), 0, stream>>>(y_pred, y_true, accp);
    ncc_finalize<<<dim3(1), dim3(1), 0, stream>>>(accp, out);
}

// Round 20
// 37.124 us; speedup vs baseline: 1.2459x; 1.1756x over previous
//
#include <hip/hip_runtime.h>

#define H 1024
#define W 1024
#define TY 16
#define NT 64               /* one wave per block */
#define RS 10               /* ring slots (distance 9 + 1) */
#define NG 66               /* uint4 groups/slot: 1 halo + 64 own + 1 halo */
#define LW 264              /* vs cols: 4 pad + 256 + 4 pad */
#define NBK 64              /* reduction buckets */

__global__ void ncc_zero(double* acc) {
    if (threadIdx.x < NBK) acc[threadIdx.x] = 0.0;
}

__global__ void ncc_finalize(const double* __restrict__ acc, float* __restrict__ out) {
    double s = 0.0;
    #pragma unroll
    for (int i = 0; i < NBK; ++i) s += acc[i];
    out[0] = 1.0f - (float)(s * (1.0 / 8388608.0));
}

__device__ __forceinline__ unsigned pk2(float lo, float hi) {
    unsigned r;
    asm("v_cvt_pk_bf16_f32 %0, %1, %2" : "=v"(r) : "v"(lo), "v"(hi));
    return r;
}
__device__ __forceinline__ float ulo(unsigned u) { return __uint_as_float(u << 16); }
__device__ __forceinline__ float uhi(unsigned u) { return __uint_as_float(u & 0xffff0000u); }

__global__ __launch_bounds__(NT) void ncc_main(
    const float* __restrict__ Jg,  // y_pred
    const float* __restrict__ Ig,  // y_true
    double* __restrict__ acc)
{
    __shared__ uint4 ring[RS][NG];     // bf16 rows {i01,i23,j01,j23}/group: 10.3 KB
    __shared__ float vs[5][LW];        // vertical sums I,J,II,JJ,IJ: 5.3 KB

    const int n     = blockIdx.x;
    const int b     = n & 7;           // image (== XCD round-robin)
    const int rest  = n >> 3;
    const int panel = rest & 3;
    const int strip = rest >> 2;
    const int y0    = strip * TY;
    const int lane  = threadIdx.x;
    const int wb    = panel << 8;
    const int x0    = wb + (lane << 2);
    const int xw    = lane << 2;       // vs read base; own at xw+4

    const float* __restrict__ Ib = Ig + (size_t)b * (H * W);
    const float* __restrict__ Jb = Jg + (size_t)b * (H * W);

    // ring halo writers: lane 0 -> group 0 (cols wb-4..wb-1), lane 1 -> group 65
    const bool  hw  = (lane < 2);
    const int   hx  = (lane == 0) ? (wb - 4) : (wb + 256);
    const float mhx = (hw && (unsigned)hx <= (unsigned)(W - 4)) ? 1.0f : 0.0f;
    const int   hxc = min(max(hx, 0), W - 4);
    const int   hgw = (lane == 0) ? 0 : (NG - 1);

    // halo-sum owners: lanes 0..7, one col each (0-3 left, 4-7 right), both images
    const bool  isH   = (lane < 8);
    const int   hg8   = (lane < 4) ? 0 : (NG - 1);
    const int   hidx  = lane & 3;
    const int   hslot = (lane < 4) ? lane : (256 + lane);   // vs pad cols 0-3 / 260-263

    float sI[4]={0,0,0,0}, sJ[4]={0,0,0,0}, sII[4]={0,0,0,0}, sJJ[4]={0,0,0,0}, sIJ[4]={0,0,0,0};
    float hs0=0, hs1=0, hs2=0, hs3=0, hs4=0;
    float accv = 0.0f;
    const float inv = 1.0f / 81.0f;

    float4 Pi, Pj, Phi = {0,0,0,0}, Phj = {0,0,0,0};
    float  Pm;

#define FLOAD(yy) do {                                                              \
        const int r_ = (yy);                                                        \
        Pm = ((unsigned)r_ < (unsigned)H) ? 1.0f : 0.0f;                            \
        const int rc_ = min(max(r_, 0), H - 1);                                     \
        Pi = *(const float4*)(Ib + (size_t)rc_ * W + x0);                           \
        Pj = *(const float4*)(Jb + (size_t)rc_ * W + x0);                           \
        if (hw) {                                                                   \
            Phi = *(const float4*)(Ib + (size_t)rc_ * W + hxc);                     \
            Phj = *(const float4*)(Jb + (size_t)rc_ * W + hxc);                     \
        }                                                                           \
    } while (0)

// pack current P-regs, write ring slot; leaves packed own-row in `pkv`
#define PACKW(sl) do {                                                              \
        pkv.x = pk2(Pi.x * Pm, Pi.y * Pm);                                          \
        pkv.y = pk2(Pi.z * Pm, Pi.w * Pm);                                          \
        pkv.z = pk2(Pj.x * Pm, Pj.y * Pm);                                          \
        pkv.w = pk2(Pj.z * Pm, Pj.w * Pm);                                          \
        ring[sl][lane + 1] = pkv;                                                   \
        if (hw) {                                                                   \
            const float mm_ = Pm * mhx;                                             \
            uint4 h_;                                                               \
            h_.x = pk2(Phi.x * mm_, Phi.y * mm_);                                   \
            h_.y = pk2(Phi.z * mm_, Phi.w * mm_);                                   \
            h_.z = pk2(Phj.x * mm_, Phj.y * mm_);                                   \
            h_.w = pk2(Phj.z * mm_, Phj.w * mm_);                                   \
            ring[sl][hgw] = h_;                                                     \
        }                                                                           \
    } while (0)

// fold packed own-4-col group into register vertical sums, sign SG
#define FOLDOWN(G, SG) do {                                                         \
        const float i0=ulo(G.x), i1=uhi(G.x), i2=ulo(G.y), i3=uhi(G.y);             \
        const float j0=ulo(G.z), j1=uhi(G.z), j2=ulo(G.w), j3=uhi(G.w);             \
        sI[0]+=SG*i0; sI[1]+=SG*i1; sI[2]+=SG*i2; sI[3]+=SG*i3;                     \
        sJ[0]+=SG*j0; sJ[1]+=SG*j1; sJ[2]+=SG*j2; sJ[3]+=SG*j3;                     \
        sII[0]+=SG*i0*i0; sII[1]+=SG*i1*i1; sII[2]+=SG*i2*i2; sII[3]+=SG*i3*i3;     \
        sJJ[0]+=SG*j0*j0; sJJ[1]+=SG*j1*j1; sJJ[2]+=SG*j2*j2; sJJ[3]+=SG*j3*j3;     \
        sIJ[0]+=SG*i0*j0; sIJ[1]+=SG*i1*j1; sIJ[2]+=SG*i2*j2; sIJ[3]+=SG*i3*j3;     \
    } while (0)

// fold one halo col (lanes 0..7) from packed halo group, sign SG
#define FOLDHALO(G, SG) do {                                                        \
        const unsigned ui_ = (hidx < 2) ? G.x : G.y;                                \
        const unsigned uj_ = (hidx < 2) ? G.z : G.w;                                \
        const float iv_ = (hidx & 1) ? uhi(ui_) : ulo(ui_);                         \
        const float jv_ = (hidx & 1) ? uhi(uj_) : ulo(uj_);                         \
        hs0 += SG*iv_; hs1 += SG*jv_;                                               \
        hs2 += SG*iv_*iv_; hs3 += SG*jv_*jv_; hs4 += SG*iv_*jv_;                    \
    } while (0)

#define PUB() do {                                                                  \
        *(float4*)&vs[0][4 + xw] = make_float4(sI[0],  sI[1],  sI[2],  sI[3]);      \
        *(float4*)&vs[1][4 + xw] = make_float4(sJ[0],  sJ[1],  sJ[2],  sJ[3]);      \
        *(float4*)&vs[2][4 + xw] = make_float4(sII[0], sII[1], sII[2], sII[3]);     \
        *(float4*)&vs[3][4 + xw] = make_float4(sJJ[0], sJJ[1], sJJ[2], sJJ[3]);     \
        *(float4*)&vs[4][4 + xw] = make_float4(sIJ[0], sIJ[1], sIJ[2], sIJ[3]);     \
        if (isH) {                                                                  \
            vs[0][hslot] = hs0; vs[1][hslot] = hs1; vs[2][hslot] = hs2;             \
            vs[3][hslot] = hs3; vs[4][hslot] = hs4;                                 \
        }                                                                           \
    } while (0)

#define HTAP(a, cg, T, o) do {                                                      \
        float s_ = a.x + a.y + a.z + a.w + cg.x + T;                                \
        o[0] = s_; s_ += cg.y - a.x;                                                \
        o[1] = s_; s_ += cg.z - a.y;                                                \
        o[2] = s_; s_ += cg.w - a.z;                                                \
        o[3] = s_;                                                                  \
    } while (0)

    // ---- init: rows y0-4 .. y0+4 -> ring slots 0..8, folded (+) ----
    FLOAD(y0 - 4);
    #pragma unroll 1
    for (int r = 0; r < 9; ++r) {
        uint4 pkv;
        PACKW(r);
        asm volatile("" ::: "memory");
        uint4 he = make_uint4(0, 0, 0, 0);
        if (isH) he = ring[r][hg8];
        asm volatile("" ::: "memory");
        FLOAD(y0 - 3 + r);             // r==8 loads y0+5: first enter row
        FOLDOWN(pkv, 1.0f);
        if (isH) FOLDHALO(he, 1.0f);
    }

    // ---- main: TY rows; uniform iteration (last slide is harmless extra) ----
    int ls = 0, es = 9;
    #pragma unroll 1
    for (int k = 0; k < TY; ++k) {
        // 1) publish window(y0+k); read neighbor halos
        PUB();
        asm volatile("" ::: "memory");
        float4 a0 = *(const float4*)&vs[0][xw], c0 = *(const float4*)&vs[0][xw + 8];
        float4 a1 = *(const float4*)&vs[1][xw], c1 = *(const float4*)&vs[1][xw + 8];
        float4 a2 = *(const float4*)&vs[2][xw], c2 = *(const float4*)&vs[2][xw + 8];
        float4 a3 = *(const float4*)&vs[3][xw], c3 = *(const float4*)&vs[3][xw + 8];
        float4 a4 = *(const float4*)&vs[4][xw], c4 = *(const float4*)&vs[4][xw + 8];
        asm volatile("" ::: "memory");

        // 2) totals of window(y0+k) before sliding
        const float T0 = sI[0]  + sI[1]  + sI[2]  + sI[3];
        const float T1 = sJ[0]  + sJ[1]  + sJ[2]  + sJ[3];
        const float T2 = sII[0] + sII[1] + sII[2] + sII[3];
        const float T3 = sJJ[0] + sJJ[1] + sJJ[2] + sJJ[3];
        const float T4 = sIJ[0] + sIJ[1] + sIJ[2] + sIJ[3];

        // 3) enter row -> ring; issue leave reads (ring) + halo reads
        uint4 pkv;
        PACKW(es);
        asm volatile("" ::: "memory");
        uint4 lv = ring[ls][lane + 1];
        uint4 he = make_uint4(0, 0, 0, 0), hl = make_uint4(0, 0, 0, 0);
        if (isH) { he = ring[es][hg8]; hl = ring[ls][hg8]; }
        asm volatile("" ::: "memory");

        // 4) prefetch next enter row (global, read-once)
        FLOAD(y0 + 6 + k);

        // 5) cc for row y0+k (covers DS latency of lv/he/hl)
        float h0[4], h1[4], h2[4], h3[4], h4[4];
        HTAP(a0, c0, T0, h0); HTAP(a1, c1, T1, h1); HTAP(a2, c2, T2, h2);
        HTAP(a3, c3, T3, h3); HTAP(a4, c4, T4, h4);
        #pragma unroll
        for (int c = 0; c < 4; ++c) {
            const float uI    = h0[c] * inv;
            const float uJ    = h1[c] * inv;
            const float cross = h4[c] * inv - uI * uJ;
            const float Iv    = h2[c] * inv - uI * uI;
            const float Jv    = h3[c] * inv - uJ * uJ;
            accv += cross * rsqrtf(fmaxf(Iv * Jv, 1e-7f));
        }

        // 6) slide: fold enter(+) / leave(-) — bit-identical packed values cancel
        FOLDOWN(pkv, 1.0f);
        FOLDOWN(lv, -1.0f);
        if (isH) { FOLDHALO(he, 1.0f); FOLDHALO(hl, -1.0f); }

        ls = (ls == RS - 1) ? 0 : ls + 1;
        es = (es == RS - 1) ? 0 : es + 1;
    }

#undef HTAP
#undef PUB
#undef FOLDHALO
#undef FOLDOWN
#undef PACKW
#undef FLOAD

    // wave reduce -> bucketed atomics
    #pragma unroll
    for (int off = 32; off > 0; off >>= 1)
        accv += __shfl_down(accv, off);
    if (lane == 0)
        atomicAdd(&acc[n & (NBK - 1)], (double)accv);
}

extern "C" void kernel_launch(void* const* d_in, const int* in_sizes, int n_in,
                              void* d_out, int out_size, void* d_ws, size_t ws_size,
                              hipStream_t stream) {
    const float* y_pred = (const float*)d_in[0];  // Ji
    const float* y_true = (const float*)d_in[1];  // Ii
    float* out = (float*)d_out;
    double* accp = (double*)d_ws;

    ncc_zero<<<dim3(1), dim3(NBK), 0, stream>>>(accp);
    // 8 img x 4 panels x 64 strips = 2048 one-wave blocks; 15.8 KB LDS;
    // register vertical sums (cheap slide) + bf16 ring (no global leave loads)
    ncc_main<<<dim3(8 * 4 * (H / TY)), dim3(NT), 0, stream>>>(y_pred, y_true, accp);
    ncc_finalize<<<dim3(1), dim3(1), 0, stream>>>(accp, out);
}